// Round 9
// baseline (251.818 us; speedup 1.0000x reference)
//
#include <hip/hip_runtime.h>
#include <hip/hip_bf16.h>
#include <math.h>

#define NS 4096          // samples per view
#define NI 8192          // total instances (2 views)
#define DIM 512          // feature dim (= 512 bytes per row in fp8)
#define TEMP_INV 2.0f    // 1/t, t = 0.5
#define NBLK 128         // NI/64 stripes
#define NGID 4096        // padded wave slots: gid = bi*32 + ci

typedef int   v4i __attribute__((ext_vector_type(4)));
typedef int   v8i __attribute__((ext_vector_type(8)));   // 32 fp8 (8 VGPRs)
typedef float v4f __attribute__((ext_vector_type(4)));   // 4 fp32 acc

// Swizzled fragment layout (verified R8, absmax 5.66e-7): for (stripe p,
// k-stage s, frag tt) a 2 KB block at ((p*4+s)*4+tt)*2048, holding
// (half h, lane) 16B granules; fragment load = two coalesced 1 KB reads.

// ---------------------------------------------------------------------------
// Kernel 1: norms + positive dots (fp32), cast X -> fp8 e4m3 into Xsw.
// Also zeroes the reduce-arrival counter.
// ---------------------------------------------------------------------------
__global__ __launch_bounds__(256) void prep_kernel(
        const float* __restrict__ x1, const float* __restrict__ x2,
        unsigned char* __restrict__ Xsw, float* __restrict__ rnorm,
        float* __restrict__ posdot, int* __restrict__ cnt) {
    const int t = threadIdx.x;
    if (blockIdx.x == 0 && t == 0) *cnt = 0;
    const int sub = t >> 7;
    const int c4 = t & 127;              // float4 index within the row
    const int i = blockIdx.x * 2 + sub;
    const float4 a = ((const float4*)(x1 + (size_t)i * DIM))[c4];
    const float4 b = ((const float4*)(x2 + (size_t)i * DIM))[c4];
    float s1 = a.x*a.x + a.y*a.y + a.z*a.z + a.w*a.w;
    float s2 = b.x*b.x + b.y*b.y + b.z*b.z + b.w*b.w;
    float dd = a.x*b.x + a.y*b.y + a.z*b.z + a.w*b.w;

    int pa = __builtin_amdgcn_cvt_pk_fp8_f32(a.x, a.y, 0, false);
    pa     = __builtin_amdgcn_cvt_pk_fp8_f32(a.z, a.w, pa, true);
    int pb = __builtin_amdgcn_cvt_pk_fp8_f32(b.x, b.y, 0, false);
    pb     = __builtin_amdgcn_cvt_pk_fp8_f32(b.z, b.w, pb, true);

    const int s   = c4 >> 5;             // k-stage (128 B each)
    const int kq  = (c4 >> 3) & 3;       // 32B quad within stage
    const int h   = (c4 >> 2) & 1;       // 16B half within quad
    const int b16 = (c4 & 3) * 4;        // byte within 16B granule
    auto dst = [&](int row) -> int* {
        const int p = row >> 6, tt = (row >> 4) & 3, r16 = row & 15;
        return (int*)(Xsw + (size_t)(((p * 4 + s) * 4 + tt) * 2048)
                          + (h * 64 + r16 + 16 * kq) * 16 + b16);
    };
    *dst(i) = pa;
    *dst(i + NS) = pb;

    #pragma unroll
    for (int off = 32; off; off >>= 1) {
        s1 += __shfl_down(s1, off, 64);
        s2 += __shfl_down(s2, off, 64);
        dd += __shfl_down(dd, off, 64);
    }
    __shared__ float red[2][2][3];
    if ((t & 63) == 0) {
        const int w = (t >> 6) & 1;
        red[sub][w][0] = s1; red[sub][w][1] = s2; red[sub][w][2] = dd;
    }
    __syncthreads();
    if ((t & 127) == 0) {
        s1 = red[sub][0][0] + red[sub][1][0];
        s2 = red[sub][0][1] + red[sub][1][1];
        dd = red[sub][0][2] + red[sub][1][2];
        rnorm[i]      = 1.0f / sqrtf(s1);
        rnorm[i + NS] = 1.0f / sqrtf(s2);
        posdot[i] = dd;
    }
}

// ---------------------------------------------------------------------------
// Kernel 2: one wave = A-stripe bi REGISTER-RESIDENT (128 VGPRs) + 4
// consecutive 64x64 tiles bj0..bj0+3. Per tile only 8 B-loads + 64 MFMAs.
// No LDS, no barriers. gid = bi*32 + ci (padded; dead waves exit).
// Epilogue: collision-free P-slice stores (R7/R8-verified).
// ---------------------------------------------------------------------------
__global__ __launch_bounds__(256) __attribute__((amdgpu_waves_per_eu(2)))
void sim_kernel(
        const unsigned char* __restrict__ Xsw, const float* __restrict__ rnorm,
        float* __restrict__ P, float* __restrict__ negpart) {
    const int t = threadIdx.x;
    const int lane = t & 63;
    const int gid = blockIdx.x * 4 + (t >> 6);      // 0..4095
    const int bi = gid >> 5;                        // 0..127
    const int ci = gid & 31;
    const int bj0 = bi + ci * 4;
    if (bj0 >= NBLK) {                              // dead slot
        if (lane == 0) negpart[gid] = 0.f;
        return;
    }
    const int i0 = bi * 64;
    const int r16 = lane & 15, quad = lane >> 4;
    const int usc = 0x7F7F7F7F;                     // unit e8m0 scales

    // --- A-stripe resident: 16 x v8i = 128 VGPRs
    const unsigned char* aS = Xsw + (size_t)bi * 32768 + (size_t)lane * 16;
    v8i af[4][4];
    #pragma unroll
    for (int s = 0; s < 4; ++s)
        #pragma unroll
        for (int tt = 0; tt < 4; ++tt) {
            const unsigned char* fa = aS + s * 8192 + tt * 2048;
            const v4i lo = *(const v4i*)(fa);
            const v4i hi = *(const v4i*)(fa + 1024);
            af[s][tt] = __builtin_shufflevector(lo, hi, 0, 1, 2, 3, 4, 5, 6, 7);
        }

    float wneg = 0.f;
    const int bjEnd = (bj0 + 4 < NBLK) ? bj0 + 4 : NBLK;

    #pragma unroll 1
    for (int bj = bj0; bj < bjEnd; ++bj) {
        const bool diag = (bj == bi);
        const int j0 = bj * 64;
        const unsigned char* bS = Xsw + (size_t)bj * 32768 + (size_t)lane * 16;

        v4f acc[4][4];
        #pragma unroll
        for (int a = 0; a < 4; ++a)
            #pragma unroll
            for (int b = 0; b < 4; ++b)
                acc[a][b] = (v4f){0.f, 0.f, 0.f, 0.f};

        #pragma unroll
        for (int s = 0; s < 4; ++s) {
            v8i bf[4];
            #pragma unroll
            for (int tt = 0; tt < 4; ++tt) {
                const unsigned char* fb = bS + s * 8192 + tt * 2048;
                const v4i lo = *(const v4i*)(fb);
                const v4i hi = *(const v4i*)(fb + 1024);
                bf[tt] = __builtin_shufflevector(lo, hi, 0, 1, 2, 3, 4, 5, 6, 7);
            }
            #pragma unroll
            for (int ta = 0; ta < 4; ++ta)
                #pragma unroll
                for (int tb = 0; tb < 4; ++tb)
                    acc[ta][tb] = __builtin_amdgcn_mfma_scale_f32_16x16x128_f8f6f4(
                        af[s][ta], bf[tb], acc[ta][tb], 0, 0, 0, usc, 0, usc);
        }

        // --- epilogue: sim2 = 2*D*r_i*r_j; masked (j==i, j==i^NS) -> exp = 1
        float rc[4];
        int colg[4];
        #pragma unroll
        for (int tb = 0; tb < 4; ++tb) {
            colg[tb] = j0 + tb * 16 + r16;
            rc[tb] = rnorm[colg[tb]];
        }
        float tneg = 0.f;
        float colacc[4] = {0.f, 0.f, 0.f, 0.f};
        #pragma unroll
        for (int ta = 0; ta < 4; ++ta) {
            #pragma unroll
            for (int r = 0; r < 4; ++r) {
                const int rowg = i0 + ta * 16 + quad * 4 + r;
                const float rr = rnorm[rowg] * TEMP_INV;
                float rowe = 0.f;
                #pragma unroll
                for (int tb = 0; tb < 4; ++tb) {
                    const float sim2 = acc[ta][tb][r] * rr * rc[tb];
                    const bool masked = (colg[tb] == rowg) || (colg[tb] == (rowg ^ NS));
                    const float e = masked ? 1.0f : __expf(sim2);
                    rowe += e;
                    tneg += masked ? 0.0f : sim2;
                    colacc[tb] += e;
                }
                #pragma unroll
                for (int off = 1; off < 16; off <<= 1)
                    rowe += __shfl_xor(rowe, off, 64);
                if (r16 == 0) P[(size_t)bj * NI + rowg] = rowe;  // one writer
            }
        }
        #pragma unroll
        for (int tb = 0; tb < 4; ++tb) {
            colacc[tb] += __shfl_xor(colacc[tb], 16, 64);
            colacc[tb] += __shfl_xor(colacc[tb], 32, 64);
            if (!diag && quad == 0) P[(size_t)bi * NI + colg[tb]] = colacc[tb];
        }
        wneg += diag ? tneg : 2.0f * tneg;
    }

    #pragma unroll
    for (int off = 1; off < 64; off <<= 1)
        wneg += __shfl_xor(wneg, off, 64);
    if (lane == 0) negpart[gid] = wneg;
}

// ---------------------------------------------------------------------------
// Kernel 3: per-row reduction of P + loss terms; last block folds the 32
// partials into the 3 output scalars (saves a launch).
// ---------------------------------------------------------------------------
__global__ __launch_bounds__(256) void reduce_kernel(
        const float* __restrict__ P, const float* __restrict__ rnorm,
        const float* __restrict__ posdot, const float* __restrict__ negpart,
        float* __restrict__ partial, int* __restrict__ cnt,
        float* __restrict__ out) {
    const int t = threadIdx.x;
    const int r = blockIdx.x * 256 + t;
    float E = 0.f;
    #pragma unroll 16
    for (int s = 0; s < NBLK; ++s)
        E += P[(size_t)s * NI + r];     // coalesced: consecutive r per s
    const float sp = posdot[r & (NS - 1)] * rnorm[r] * rnorm[r ^ NS] * TEMP_INV;
    float lsum = logf(expf(sp) + E) - sp;
    float psum = sp;
    const int gi = blockIdx.x * 256 + t;
    float nsum = (gi < NGID) ? negpart[gi] : 0.f;

    __shared__ float red[3][4];
    #pragma unroll
    for (int off = 32; off; off >>= 1) {
        lsum += __shfl_down(lsum, off, 64);
        psum += __shfl_down(psum, off, 64);
        nsum += __shfl_down(nsum, off, 64);
    }
    if ((t & 63) == 0) {
        red[0][t >> 6] = lsum; red[1][t >> 6] = psum; red[2][t >> 6] = nsum;
    }
    __syncthreads();
    __shared__ int lastFlag;
    if (t == 0) {
        lsum = red[0][0] + red[0][1] + red[0][2] + red[0][3];
        psum = red[1][0] + red[1][1] + red[1][2] + red[1][3];
        nsum = red[2][0] + red[2][1] + red[2][2] + red[2][3];
        partial[blockIdx.x * 3 + 0] = lsum;
        partial[blockIdx.x * 3 + 1] = psum;
        partial[blockIdx.x * 3 + 2] = nsum;
        __threadfence();
        lastFlag = (atomicAdd(cnt, 1) == 31);
    }
    __syncthreads();
    if (lastFlag) {
        float l = 0.f, p = 0.f, n = 0.f;
        if (t < 32) {
            l = partial[t * 3 + 0];
            p = partial[t * 3 + 1];
            n = partial[t * 3 + 2];
        }
        #pragma unroll
        for (int off = 1; off < 32; off <<= 1) {
            l += __shfl_xor(l, off, 64);
            p += __shfl_xor(p, off, 64);
            n += __shfl_xor(n, off, 64);
        }
        if (t == 0) {
            out[0] = l / (float)NI;
            out[1] = p / (float)NI;
            out[2] = n / ((float)NI * (float)(NI - 2));
        }
    }
}

// ---------------------------------------------------------------------------
extern "C" void kernel_launch(void* const* d_in, const int* in_sizes, int n_in,
                              void* d_out, int out_size, void* d_ws, size_t ws_size,
                              hipStream_t stream) {
    const float* x1 = (const float*)d_in[0];
    const float* x2 = (const float*)d_in[1];
    float* out = (float*)d_out;

    char* ws = (char*)d_ws;
    unsigned char* Xsw = (unsigned char*)ws;                  // NI*DIM = 4 MB
    float* P       = (float*)(ws + (size_t)NI * DIM);         // 128*8192*4 = 4 MB
    float* rnorm   = (float*)(ws + 2 * (size_t)NI * DIM);     // NI
    float* posdot  = rnorm + NI;                              // NS
    float* negpart = posdot + NS;                             // NGID (all written)
    float* partial = negpart + NGID;                          // 96
    int*   cnt     = (int*)(partial + 96);                    // 1 (zeroed in prep)
    // Every P slot / negpart / partial entry is written before being read.

    prep_kernel<<<NS / 2, 256, 0, stream>>>(x1, x2, Xsw, rnorm, posdot, cnt);

    sim_kernel<<<NGID / 4, 256, 0, stream>>>(Xsw, rnorm, P, negpart);

    reduce_kernel<<<32, 256, 0, stream>>>(P, rnorm, posdot, negpart,
                                          partial, cnt, out);
}